// Round 1
// baseline (57.712 us; speedup 1.0000x reference)
//
#include <hip/hip_runtime.h>
#include <math.h>

#define SEQ 4096
#define TPB 1024
#define CHUNK (SEQ / TPB)  // 4
#define NWAVE (TPB / 64)   // 16

__global__ __launch_bounds__(TPB) void probs_to_span_kernel(
    const float* __restrict__ start_p,
    const float* __restrict__ end_p,
    float* __restrict__ out, int B) {
  const int b = blockIdx.x;
  const int t = threadIdx.x;
  const int lane = t & 63;
  const int wave = t >> 6;

  // Perfectly coalesced: lane stride = 16 B, one wave load = contiguous 1 KB.
  const float4 sv = *(const float4*)(start_p + (size_t)b * SEQ + t * CHUNK);
  const float4 ev = *(const float4*)(end_p + (size_t)b * SEQ + t * CHUNK);
  float s_vals[CHUNK] = {sv.x, sv.y, sv.z, sv.w};
  float e_vals[CHUNK] = {ev.x, ev.y, ev.z, ev.w};

  // Per-chunk maxima.
  float cmax_s = fmaxf(fmaxf(s_vals[0], s_vals[1]), fmaxf(s_vals[2], s_vals[3]));
  float cmax_e = fmaxf(fmaxf(e_vals[0], e_vals[1]), fmaxf(e_vals[2], e_vals[3]));

  // ---- Wave-parallel scans over the chunk maxima ----
  // Inclusive prefix-max scan of cmax_s within the wave (shfl_up).
  float xs = cmax_s;
#pragma unroll
  for (int off = 1; off < 64; off <<= 1) {
    float v = __shfl_up(xs, off, 64);
    if (lane >= off) xs = fmaxf(xs, v);
  }
  float ex_pref = (lane == 0) ? -INFINITY : __shfl_up(xs, 1, 64);  // exclusive, intra-wave
  float wave_tot_s = __shfl(xs, 63, 64);                           // wave's full max

  // Inclusive suffix-max scan of cmax_e within the wave (shfl_down).
  float xe = cmax_e;
#pragma unroll
  for (int off = 1; off < 64; off <<= 1) {
    float v = __shfl_down(xe, off, 64);
    if (lane < 64 - off) xe = fmaxf(xe, v);
  }
  float ex_suff = (lane == 63) ? -INFINITY : __shfl_down(xe, 1, 64);
  float wave_tot_e = __shfl(xe, 0, 64);

  // Combine across the 16 waves via LDS (broadcast reads, no bank conflicts).
  __shared__ float sh_tot_s[NWAVE], sh_tot_e[NWAVE];
  if (lane == 0) { sh_tot_s[wave] = wave_tot_s; sh_tot_e[wave] = wave_tot_e; }
  __syncthreads();
  float wpref = -INFINITY, wsuff = -INFINITY;
#pragma unroll
  for (int w = 0; w < NWAVE; ++w) {
    if (w < wave) wpref = fmaxf(wpref, sh_tot_s[w]);
    if (w > wave) wsuff = fmaxf(wsuff, sh_tot_e[w]);
  }
  float pref = fmaxf(wpref, ex_pref);  // exclusive prefix-max of start chunk-maxima
  float suff = fmaxf(wsuff, ex_suff);  // exclusive suffix-max of end chunk-maxima

  // ---- predicted_start: row_max[s] = start[s] * suffmax_end[s] (t >= s) ----
  float suffm[CHUNK];
  float run = suff;
#pragma unroll
  for (int k = CHUNK - 1; k >= 0; --k) {
    run = fmaxf(run, e_vals[k]);
    suffm[k] = run;
  }
  float bestv = -INFINITY; int besti = 0;
#pragma unroll
  for (int k = 0; k < CHUNK; ++k) {
    float v = s_vals[k] * suffm[k];
    if (v > bestv) { bestv = v; besti = t * CHUNK + k; }  // strict > = first occurrence
  }

  // ---- predicted_end: col_max[t] = end[t] * prefmax_start[t] (s <= t) ----
  run = pref;
  float bestv2 = -INFINITY; int besti2 = 0;
#pragma unroll
  for (int k = 0; k < CHUNK; ++k) {
    run = fmaxf(run, s_vals[k]);
    float v = e_vals[k] * run;
    if (v > bestv2) { bestv2 = v; besti2 = t * CHUNK + k; }
  }

  // ---- In-wave argmax reductions (lane i's span is lower-indexed than lane i+off's,
  //      so strict > keeps the first occurrence). ----
#pragma unroll
  for (int off = 32; off > 0; off >>= 1) {
    float ov = __shfl_down(bestv, off, 64);
    int   oi = __shfl_down(besti, off, 64);
    if (ov > bestv) { bestv = ov; besti = oi; }
    float ov2 = __shfl_down(bestv2, off, 64);
    int   oi2 = __shfl_down(besti2, off, 64);
    if (ov2 > bestv2) { bestv2 = ov2; besti2 = oi2; }
  }

  // Combine the 16 wave champions (ascending wave order = ascending index ranges).
  __shared__ float sh_v[NWAVE], sh_v2[NWAVE];
  __shared__ int   sh_i[NWAVE], sh_i2[NWAVE];
  if (lane == 0) { sh_v[wave] = bestv; sh_i[wave] = besti;
                   sh_v2[wave] = bestv2; sh_i2[wave] = besti2; }
  __syncthreads();
  if (t == 0) {
    float fv = sh_v[0];  int fi = sh_i[0];
    float fv2 = sh_v2[0]; int fi2 = sh_i2[0];
#pragma unroll
    for (int w = 1; w < NWAVE; ++w) {
      if (sh_v[w] > fv)   { fv = sh_v[w];   fi = sh_i[w]; }
      if (sh_v2[w] > fv2) { fv2 = sh_v2[w]; fi2 = sh_i2[w]; }
    }
    out[b] = (float)fi;       // predicted_start
    out[B + b] = (float)fi2;  // predicted_end
  }
}

extern "C" void kernel_launch(void* const* d_in, const int* in_sizes, int n_in,
                              void* d_out, int out_size, void* d_ws, size_t ws_size,
                              hipStream_t stream) {
  const float* start_p = (const float*)d_in[0];
  const float* end_p = (const float*)d_in[1];
  float* out = (float*)d_out;
  const int B = in_sizes[0] / SEQ;  // 16
  probs_to_span_kernel<<<B, TPB, 0, stream>>>(start_p, end_p, out, B);
}